// Round 11
// baseline (310.418 us; speedup 1.0000x reference)
//
#include <hip/hip_runtime.h>
#include <stdint.h>

#define N_NODES 131072
#define HDIM 128

typedef __bf16 bf16x8 __attribute__((ext_vector_type(8)));
typedef float f32x4 __attribute__((ext_vector_type(4)));
typedef unsigned short ushort_t;

__device__ __forceinline__ ushort_t f2bf(float f) {
    union { float f; uint32_t i; } v; v.f = f;
    uint32_t i = v.i;
    return (ushort_t)((i + 0x7FFFu + ((i >> 16) & 1u)) >> 16);  // RNE
}

// async global->LDS 16B DMA: LDS dest = wave-uniform base + lane*16
__device__ __forceinline__ void gll16(const ushort_t* g, ushort_t* l) {
    __builtin_amdgcn_global_load_lds(
        (const __attribute__((address_space(1))) uint32_t*)g,
        (__attribute__((address_space(3))) uint32_t*)l, 16, 0, 0);
}

// BK=64 rot swizzle (l2): LDS row r slot c holds global chunk (c+r)&7
// [verified: SQ_LDS_BANK_CONFLICT -> 0 at this pattern]
__device__ __forceinline__ bf16x8 ldsw(const ushort_t* base, int R, int g) {
    return *(const bf16x8*)&base[R * 64 + (((g - R) & 7) << 3)];
}

// BK=128 rot swizzle (l1 B-tile): row r slot s holds global chunk (s+r)&15.
// Read of chunk g at row R -> slot (g-R)&15; 16 lanes cover all 16 slots ->
// 2 lanes/bank-group = free 2-way aliasing (m136).
__device__ __forceinline__ bf16x8 ldsw128(const ushort_t* base, int R, int g) {
    return *(const bf16x8*)&base[R * 128 + (((g - R) & 15) << 3)];
}

// fast sigmoid / tanh via v_exp_f32 + v_rcp_f32 (bf16-accurate)
__device__ __forceinline__ float fsig(float x) {
    return __builtin_amdgcn_rcpf(1.0f + __expf(-x));
}
__device__ __forceinline__ float ftanh(float y) {
    float yc = fminf(fmaxf(y, -15.0f), 15.0f);
    float e = __expf(2.0f * yc);
    return (e - 1.0f) * __builtin_amdgcn_rcpf(e + 1.0f);
}

// XCD-temporal block swizzle, NC=8 [verified: FETCH 264->34 MB]
template<int NC>
__device__ __forceinline__ void swz(int b, int& m, int& c) {
    int mhi = b / (8 * NC);
    int rem = b - mhi * (8 * NC);
    c = rem >> 3;
    m = mhi * 8 + (rem & 7);
}

// ---------------------------------------------------------------------------
// prep_all: blocks 0..1151 = fp32->bf16 GRU weight conversion; block 1152 =
// prep_M (T1 = w_g2@w_fc; M = w_g1@T1 -> M16; cc corrections). [validated]
// ---------------------------------------------------------------------------
__global__ __launch_bounds__(256) void prep_all(
    const float* __restrict__ w_f1, const float* __restrict__ w_b1,
    const float* __restrict__ w_f2, const float* __restrict__ w_b2,
    ushort_t* __restrict__ PWF1, ushort_t* __restrict__ PWB1,
    ushort_t* __restrict__ PWF2, ushort_t* __restrict__ PWB2,
    const float* __restrict__ w_g1, const float* __restrict__ b_g1,
    const float* __restrict__ w_g2, const float* __restrict__ b_g2,
    const float* __restrict__ w_fc, const float* __restrict__ b_fc,
    ushort_t* __restrict__ M16, float* __restrict__ cc)
{
    __shared__ float wfc_s[640];
    __shared__ float T1[128][10];
    const int t = threadIdx.x;

    if (blockIdx.x < 1152) {
        int idx = blockIdx.x * 256 + t;
        if (idx < 49152) {
            PWF1[idx] = f2bf(w_f1[idx]);
        } else if (idx < 98304) {
            int j = idx - 49152;  PWB1[j] = f2bf(w_b1[j]);
        } else if (idx < 196608) {
            int j = idx - 98304;  PWF2[j] = f2bf(w_f2[j]);
        } else if (idx < 294912) {
            int j = idx - 196608; PWB2[j] = f2bf(w_b2[j]);
        }
        return;
    }

    // ---- prep_M (single block) ----
    for (int i = t; i < 640; i += 256) wfc_s[i] = w_fc[i];
    __syncthreads();
    if (t < 128) {
        float s[10];
        #pragma unroll
        for (int j = 0; j < 10; ++j) s[j] = 0.0f;
        const float4* row = (const float4*)(w_g2 + t * 64);
        #pragma unroll
        for (int k4 = 0; k4 < 16; ++k4) {
            float4 v = row[k4];
            #pragma unroll
            for (int j = 0; j < 10; ++j)
                s[j] += v.x * wfc_s[(k4 * 4 + 0) * 10 + j] + v.y * wfc_s[(k4 * 4 + 1) * 10 + j]
                      + v.z * wfc_s[(k4 * 4 + 2) * 10 + j] + v.w * wfc_s[(k4 * 4 + 3) * 10 + j];
        }
        #pragma unroll
        for (int j = 0; j < 10; ++j) T1[t][j] = s[j];
    }
    __syncthreads();
    float m[10];
    #pragma unroll
    for (int j = 0; j < 10; ++j) m[j] = 0.0f;
    const float4* row1 = (const float4*)(w_g1 + t * 128);
    #pragma unroll 4
    for (int k4 = 0; k4 < 32; ++k4) {
        float4 v = row1[k4];
        #pragma unroll
        for (int j = 0; j < 10; ++j)
            m[j] += v.x * T1[k4 * 4 + 0][j] + v.y * T1[k4 * 4 + 1][j]
                  + v.z * T1[k4 * 4 + 2][j] + v.w * T1[k4 * 4 + 3][j];
    }
    #pragma unroll
    for (int j = 0; j < 16; ++j)
        M16[j * 256 + t] = (j < 10) ? f2bf(m[j]) : (ushort_t)0;
    if (t < 10) {
        float s1 = 0.0f;
        for (int k2 = 0; k2 < 128; ++k2) s1 += b_g1[k2] * T1[k2][t];
        cc[t] = s1;
        float s2 = 0.0f;
        for (int k3 = 0; k3 < 64; ++k3) s2 += b_g2[k3] * wfc_s[k3 * 10 + t];
        cc[16 + t] = s2 + b_fc[t];
    }
}

// ---------------------------------------------------------------------------
// GRU layer 1 — A-IN-REGISTERS [R10 post-mortem: A-resident-LDS hit the
// 4-work/3-resident tail (Occ 37%)]. Per wave: 16 rows; per lane the whole
// K=128 A-slice = 4 MFMA frags (16 VGPR), loaded straight from global X in
// m89 fragment layout (same RNE cvt -> h1 bit-identical). LDS = Bs 24 KB
// only -> with <=64 VGPR (launch_bounds 512,8) 4 blocks/CU resident =
// PERFECT fit for grid 1024 (zero tail). One 24 KB B-stage + 24 MFMA per jc
// -> barriers halve (32->16).
// ---------------------------------------------------------------------------
__global__ __launch_bounds__(512, 8) void gru_l1(
    const float* __restrict__ X,         // [N,128] fp32
    const ushort_t* __restrict__ Wf,     // [384,128] bf16
    const ushort_t* __restrict__ Wb,
    const float* __restrict__ bi_f, const float* __restrict__ bh_f,
    const float* __restrict__ bi_b, const float* __restrict__ bh_b,
    ushort_t* __restrict__ Hout)         // [N,256] bf16
{
    __shared__ ushort_t Bs[96 * 128];    // 24 KB (one jc's 3-gate W slice, K=128)
    const int tid = threadIdx.x;
    const int m0 = blockIdx.x * 128;
    const int wv = tid >> 6, lane = tid & 63;
    const int lr = lane & 15, lq = lane >> 4;

    // A-frags from global: af[c] = X[m0 + wv*16 + lr][c*32 + lq*8 .. +7]
    bf16x8 af[4];
    {
        const float* xr = X + (size_t)(m0 + wv * 16 + lr) * 128 + lq * 8;
        #pragma unroll
        for (int c = 0; c < 4; ++c) {
            float4 f0 = ((const float4*)(xr + c * 32))[0];
            float4 f1 = ((const float4*)(xr + c * 32))[1];
            bf16x8 t8;
            t8[0] = (__bf16)f0.x; t8[1] = (__bf16)f0.y;
            t8[2] = (__bf16)f0.z; t8[3] = (__bf16)f0.w;
            t8[4] = (__bf16)f1.x; t8[5] = (__bf16)f1.y;
            t8[6] = (__bf16)f1.z; t8[7] = (__bf16)f1.w;
            af[c] = t8;
        }
    }

    for (int jc = 0; jc < 8; ++jc) {
        const int dir = jc >> 2;
        const int j0 = (jc & 3) * 32;
        const ushort_t* W = dir ? Wb : Wf;
        const float* b_ih = dir ? bi_b : bi_f;
        const float* b_hh = dir ? bh_b : bh_f;
        const int coloff = dir << 7;

        // stage B: 1536 chunks (96 rows x 16 slots), rot-swizzled, 3/thread
        #pragma unroll
        for (int p = 0; p < 3; ++p) {
            int ci = p * 512 + tid;
            int r96 = ci >> 4, slot = ci & 15;
            int g16 = (slot + r96) & 15;
            int wr = ((r96 >> 5) << 7) + j0 + (r96 & 31);
            gll16(W + (size_t)wr * 128 + g16 * 8, &Bs[ci * 8]);
        }
        __syncthreads();

        f32x4 acc[3][2];
        #pragma unroll
        for (int g = 0; g < 3; ++g)
            #pragma unroll
            for (int ct = 0; ct < 2; ++ct)
                #pragma unroll
                for (int e = 0; e < 4; ++e) acc[g][ct][e] = 0.0f;

        #pragma unroll
        for (int c = 0; c < 4; ++c) {          // k = c*32 .. +31 (ascending)
            #pragma unroll
            for (int g = 0; g < 3; ++g) {
                #pragma unroll
                for (int ct = 0; ct < 2; ++ct) {
                    bf16x8 b = ldsw128(Bs, g * 32 + ct * 16 + lr, c * 4 + lq);
                    acc[g][ct] = __builtin_amdgcn_mfma_f32_16x16x32_bf16(af[c], b, acc[g][ct], 0, 0, 0);
                }
            }
        }

        // epilogue jc: C/D layout col=lane&15, row=(lane>>4)*4+reg [m89/m91]
        #pragma unroll
        for (int ct = 0; ct < 2; ++ct) {
            const int j = j0 + ct * 16 + lr;
            const float br  = b_ih[j] + b_hh[j];
            const float bz  = b_ih[HDIM + j] + b_hh[HDIM + j];
            const float bn  = b_ih[2 * HDIM + j];
            const float bhn = b_hh[2 * HDIM + j];
            #pragma unroll
            for (int r = 0; r < 4; ++r) {
                const int row = m0 + wv * 16 + lq * 4 + r;
                float rg = fsig(acc[0][ct][r] + br);
                float zg = fsig(acc[1][ct][r] + bz);
                float ng = ftanh(acc[2][ct][r] + bn + rg * bhn);
                ((__bf16*)Hout)[(size_t)row * 256 + coloff + j] = (__bf16)((1.0f - zg) * ng);
            }
        }
        __syncthreads();                 // all reads of Bs done before next jc
    }
}

// ---------------------------------------------------------------------------
// GRU layer 2 + fused z-projection [R7's exact kernel — best measured 73 us].
// h2 never hits HBM; per-wave 32x32 spill stride 40; per-comb Zp slice.
// ---------------------------------------------------------------------------
__global__ __launch_bounds__(256, 5) void gru_l2(
    const ushort_t* __restrict__ A,      // h1 [N,256] bf16
    const ushort_t* __restrict__ Wf,     // [384,256] bf16
    const ushort_t* __restrict__ Wb,
    const float* __restrict__ bi_f, const float* __restrict__ bh_f,
    const float* __restrict__ bi_b, const float* __restrict__ bh_b,
    const ushort_t* __restrict__ M16,    // [16,256] bf16
    float* __restrict__ Zp)              // [8][N][10] fp32 partial slices
{
    __shared__ ushort_t As[128 * 64];    // 16 KB
    __shared__ ushort_t Bs[96 * 64];     // 12 KB
    const int tid = threadIdx.x;
    int mt, comb;
    swz<8>(blockIdx.x, mt, comb);
    const int m0 = mt * 128;
    const int dir = comb >> 2;
    const int j0 = (comb & 3) * 32;
    const ushort_t* W = dir ? Wb : Wf;
    const float* b_ih = dir ? bi_b : bi_f;
    const float* b_hh = dir ? bh_b : bh_f;
    const int coloff = dir << 7;

    const int wv = tid >> 6, lane = tid & 63;
    const int lr = lane & 15, lq = lane >> 4;
    const int tr = tid >> 3, tc = tid & 7;
    const int sc = ((tr + tc) & 7) << 3;

    f32x4 acc[3][2][2];
    #pragma unroll
    for (int g = 0; g < 3; ++g)
        #pragma unroll
        for (int rt = 0; rt < 2; ++rt)
            #pragma unroll
            for (int ct = 0; ct < 2; ++ct)
                #pragma unroll
                for (int e = 0; e < 4; ++e) acc[g][rt][ct][e] = 0.0f;

    for (int t = 0; t < 4; ++t) {
        const int k0 = t * 64;
        const ushort_t* ga = A + (size_t)(m0 + tr) * 256 + k0 + sc;
        #pragma unroll
        for (int i = 0; i < 4; ++i)
            gll16(ga + (size_t)i * 32 * 256, &As[(i * 256 + tid) * 8]);
        #pragma unroll
        for (int i = 0; i < 3; ++i) {
            int wr = (i << 7) + j0 + tr;
            gll16(W + (size_t)wr * 256 + k0 + sc, &Bs[(i * 256 + tid) * 8]);
        }
        __syncthreads();
        #pragma unroll
        for (int kk = 0; kk < 64; kk += 32) {
            const int g8 = (kk >> 3) + lq;
            bf16x8 a0 = ldsw(As, wv * 32 + lr, g8);
            bf16x8 a1 = ldsw(As, wv * 32 + 16 + lr, g8);
            #pragma unroll
            for (int g = 0; g < 3; ++g) {
                #pragma unroll
                for (int ct = 0; ct < 2; ++ct) {
                    bf16x8 b = ldsw(Bs, g * 32 + ct * 16 + lr, g8);
                    acc[g][0][ct] = __builtin_amdgcn_mfma_f32_16x16x32_bf16(a0, b, acc[g][0][ct], 0, 0, 0);
                    acc[g][1][ct] = __builtin_amdgcn_mfma_f32_16x16x32_bf16(a1, b, acc[g][1][ct], 0, 0, 0);
                }
            }
        }
        __syncthreads();
    }

    // B-frag for z: lane holds M16[n=lr][k = coloff+j0 + lq*8 .. +7] (L2-hot)
    const bf16x8 mb = *(const bf16x8*)&M16[lr * 256 + coloff + j0 + lq * 8];

    // epilogue: compute h, spill per-wave 32x32 tile at row stride 40 shorts
    ushort_t* hs = &As[wv * 1280];       // 32 rows * 40 shorts = 2560 B/wave
    #pragma unroll
    for (int ct = 0; ct < 2; ++ct) {
        const int j = j0 + ct * 16 + lr;
        const float br  = b_ih[j] + b_hh[j];
        const float bz  = b_ih[HDIM + j] + b_hh[HDIM + j];
        const float bn  = b_ih[2 * HDIM + j];
        const float bhn = b_hh[2 * HDIM + j];
        #pragma unroll
        for (int rt = 0; rt < 2; ++rt) {
            #pragma unroll
            for (int r = 0; r < 4; ++r) {
                const int lrow = rt * 16 + lq * 4 + r;
                float rg = fsig(acc[0][rt][ct][r] + br);
                float zg = fsig(acc[1][rt][ct][r] + bz);
                float ng = ftanh(acc[2][rt][ct][r] + bn + rg * bhn);
                ((__bf16*)hs)[lrow * 40 + ct * 16 + lr] = (__bf16)((1.0f - zg) * ng);
            }
        }
    }
    __syncthreads();

    // A-frags from own wave band: row = rt*16 + lr, k = lq*8..+7
    bf16x8 ha0 = *(const bf16x8*)&hs[lr * 40 + lq * 8];
    bf16x8 ha1 = *(const bf16x8*)&hs[(16 + lr) * 40 + lq * 8];
    f32x4 z0, z1;
    #pragma unroll
    for (int e = 0; e < 4; ++e) { z0[e] = 0.0f; z1[e] = 0.0f; }
    z0 = __builtin_amdgcn_mfma_f32_16x16x32_bf16(ha0, mb, z0, 0, 0, 0);
    z1 = __builtin_amdgcn_mfma_f32_16x16x32_bf16(ha1, mb, z1, 0, 0, 0);

    if (lr < 10) {
        float* zslice = Zp + (size_t)comb * ((size_t)N_NODES * 10);
        #pragma unroll
        for (int r = 0; r < 4; ++r) {
            zslice[(size_t)(m0 + wv * 32 + lq * 4 + r) * 10 + lr] = z0[r];
            zslice[(size_t)(m0 + wv * 32 + 16 + lq * 4 + r) * 10 + lr] = z1[r];
        }
    }
}

// ---------------------------------------------------------------------------
// stz: merged zsum + st5 [R7/R10-validated]. Interior blocks float4-vectorized
// 8-slice sum; edge blocks scalar. Then 5-point stencil + bias corrections.
// ---------------------------------------------------------------------------
__device__ __forceinline__ float dcoef(int i) {
    return (i == 0 || i == N_NODES - 1) ? 0.70710678118654752f : 0.57735026918962576f;
}
__global__ __launch_bounds__(256) void stz(
    const float* __restrict__ Zp, float* __restrict__ out,
    const float* __restrict__ cc)
{
    __shared__ __align__(16) float zl[2600];   // 260 nodes x 10
    const int tid = threadIdx.x;
    const int n0 = blockIdx.x * 256;
    const bool edge = (blockIdx.x == 0) || (blockIdx.x == gridDim.x - 1);

    if (!edge) {
        const size_t base4 = ((size_t)n0 * 10 - 20) >> 2;
        const float4* Z4 = (const float4*)Zp;
        for (int i4 = tid; i4 < 650; i4 += 256) {
            float4 a = Z4[base4 + i4];
            #pragma unroll
            for (int s = 1; s < 8; ++s) {
                float4 b = Z4[(size_t)s * ((size_t)N_NODES * 10 / 4) + base4 + i4];
                a.x += b.x; a.y += b.y; a.z += b.z; a.w += b.w;
            }
            ((float4*)zl)[i4] = a;
        }
    } else {
        for (int i = tid; i < 2600; i += 256) {
            int nl = i / 10;
            int c = i - nl * 10;
            int n = n0 - 2 + nl;
            float v = 0.0f;
            if (n >= 0 && n < N_NODES) {
                size_t b = (size_t)n * 10 + c;
                #pragma unroll
                for (int s = 0; s < 8; ++s)
                    v += Zp[(size_t)s * ((size_t)N_NODES * 10) + b];
            }
            zl[i] = v;
        }
    }
    __syncthreads();

    const int i = n0 + tid;
    const float d_i = dcoef(i);
    float dsum = d_i;
    if (i - 1 >= 0) dsum += dcoef(i - 1);
    if (i + 1 < N_NODES) dsum += dcoef(i + 1);

    #pragma unroll
    for (int c = 0; c < 10; ++c) {
        float accv = 0.0f;
        #pragma unroll
        for (int oj = -1; oj <= 1; ++oj) {
            int j = i + oj;
            if (j < 0 || j >= N_NODES) continue;
            float dj = dcoef(j);
            float wj = 0.0f;
            #pragma unroll
            for (int ok = -1; ok <= 1; ++ok) {
                int k = j + ok;
                wj += dcoef(k) * zl[(tid + 2 + oj + ok) * 10 + c];
            }
            accv += dj * dj * wj;
        }
        out[(size_t)i * 10 + c] = d_i * accv + d_i * dsum * cc[c] + cc[16 + c];
    }
}

extern "C" void kernel_launch(void* const* d_in, const int* in_sizes, int n_in,
                              void* d_out, int out_size, void* d_ws, size_t ws_size,
                              hipStream_t stream) {
    const float* x     = (const float*)d_in[0];
    const float* w_f1  = (const float*)d_in[1];
    const float* bi_f1 = (const float*)d_in[2];
    const float* bh_f1 = (const float*)d_in[3];
    const float* w_b1  = (const float*)d_in[4];
    const float* bi_b1 = (const float*)d_in[5];
    const float* bh_b1 = (const float*)d_in[6];
    const float* w_f2  = (const float*)d_in[7];
    const float* bi_f2 = (const float*)d_in[8];
    const float* bh_f2 = (const float*)d_in[9];
    const float* w_b2  = (const float*)d_in[10];
    const float* bi_b2 = (const float*)d_in[11];
    const float* bh_b2 = (const float*)d_in[12];
    const float* w_g1  = (const float*)d_in[13];
    const float* b_g1  = (const float*)d_in[14];
    const float* w_g2  = (const float*)d_in[15];
    const float* b_g2  = (const float*)d_in[16];
    const float* w_fc  = (const float*)d_in[17];
    const float* b_fc  = (const float*)d_in[18];

    char* ws = (char*)d_ws;
    ushort_t* h1   = (ushort_t*)(ws);                    // [N,256] bf16 (67.1 MB)
    float*    Zp   = (float*)(ws + 67108864);            // [8][N,10] fp32 (41.9 MB)
    ushort_t* PWF1 = (ushort_t*)(ws + 134217728);        // [384,128] bf16
    ushort_t* PWB1 = PWF1 + 49152;
    ushort_t* PWF2 = PWB1 + 49152;                       // [384,256] bf16
    ushort_t* PWB2 = PWF2 + 98304;
    ushort_t* M16  = PWB2 + 98304;                       // [16,256] bf16
    float*    cc   = (float*)(M16 + 4096);               // cc1[0..9], cc2[16..25]

    prep_all<<<1153, 256, 0, stream>>>(w_f1, w_b1, w_f2, w_b2,
                                       PWF1, PWB1, PWF2, PWB2,
                                       w_g1, b_g1, w_g2, b_g2, w_fc, b_fc,
                                       M16, cc);

    gru_l1<<<N_NODES / 128, 512, 0, stream>>>(
        x, PWF1, PWB1, bi_f1, bh_f1, bi_b1, bh_b1, h1);
    gru_l2<<<N_NODES / 128 * 8, 256, 0, stream>>>(
        h1, PWF2, PWB2, bi_f2, bh_f2, bi_b2, bh_b2, M16, Zp);

    stz<<<N_NODES / 256, 256, 0, stream>>>(Zp, (float*)d_out, cc);
}

// Round 12
// 269.723 us; speedup vs baseline: 1.1509x; 1.1509x over previous
//
#include <hip/hip_runtime.h>
#include <stdint.h>

#define N_NODES 131072
#define HDIM 128

typedef __bf16 bf16x8 __attribute__((ext_vector_type(8)));
typedef float f32x4 __attribute__((ext_vector_type(4)));
typedef unsigned short ushort_t;

__device__ __forceinline__ ushort_t f2bf(float f) {
    union { float f; uint32_t i; } v; v.f = f;
    uint32_t i = v.i;
    return (ushort_t)((i + 0x7FFFu + ((i >> 16) & 1u)) >> 16);  // RNE
}

// async global->LDS 16B DMA: LDS dest = wave-uniform base + lane*16
__device__ __forceinline__ void gll16(const ushort_t* g, ushort_t* l) {
    __builtin_amdgcn_global_load_lds(
        (const __attribute__((address_space(1))) uint32_t*)g,
        (__attribute__((address_space(3))) uint32_t*)l, 16, 0, 0);
}

// BK=64 rot swizzle: LDS row r slot c holds global chunk (c+r)&7 (16B chunks)
// [verified: SQ_LDS_BANK_CONFLICT -> 0 at this pattern]
__device__ __forceinline__ bf16x8 ldsw(const ushort_t* base, int R, int g) {
    return *(const bf16x8*)&base[R * 64 + (((g - R) & 7) << 3)];
}

// fast sigmoid / tanh via v_exp_f32 + v_rcp_f32 (bf16-accurate)
__device__ __forceinline__ float fsig(float x) {
    return __builtin_amdgcn_rcpf(1.0f + __expf(-x));
}
__device__ __forceinline__ float ftanh(float y) {
    float yc = fminf(fmaxf(y, -15.0f), 15.0f);
    float e = __expf(2.0f * yc);
    return (e - 1.0f) * __builtin_amdgcn_rcpf(e + 1.0f);
}

// ---------------------------------------------------------------------------
// prep_all: blocks 0..1151 = fp32->bf16 GRU weight conversion; block 1152 =
// prep_M (T1 = w_g2@w_fc; M = w_g1@T1 -> M16; cc corrections). [validated]
// ---------------------------------------------------------------------------
__global__ __launch_bounds__(256) void prep_all(
    const float* __restrict__ w_f1, const float* __restrict__ w_b1,
    const float* __restrict__ w_f2, const float* __restrict__ w_b2,
    ushort_t* __restrict__ PWF1, ushort_t* __restrict__ PWB1,
    ushort_t* __restrict__ PWF2, ushort_t* __restrict__ PWB2,
    const float* __restrict__ w_g1, const float* __restrict__ b_g1,
    const float* __restrict__ w_g2, const float* __restrict__ b_g2,
    const float* __restrict__ w_fc, const float* __restrict__ b_fc,
    ushort_t* __restrict__ M16, float* __restrict__ cc)
{
    __shared__ float wfc_s[640];
    __shared__ float T1[128][10];
    const int t = threadIdx.x;

    if (blockIdx.x < 1152) {
        int idx = blockIdx.x * 256 + t;
        if (idx < 49152) {
            PWF1[idx] = f2bf(w_f1[idx]);
        } else if (idx < 98304) {
            int j = idx - 49152;  PWB1[j] = f2bf(w_b1[j]);
        } else if (idx < 196608) {
            int j = idx - 98304;  PWF2[j] = f2bf(w_f2[j]);
        } else if (idx < 294912) {
            int j = idx - 196608; PWB2[j] = f2bf(w_b2[j]);
        }
        return;
    }

    // ---- prep_M (single block) ----
    for (int i = t; i < 640; i += 256) wfc_s[i] = w_fc[i];
    __syncthreads();
    if (t < 128) {
        float s[10];
        #pragma unroll
        for (int j = 0; j < 10; ++j) s[j] = 0.0f;
        const float4* row = (const float4*)(w_g2 + t * 64);
        #pragma unroll
        for (int k4 = 0; k4 < 16; ++k4) {
            float4 v = row[k4];
            #pragma unroll
            for (int j = 0; j < 10; ++j)
                s[j] += v.x * wfc_s[(k4 * 4 + 0) * 10 + j] + v.y * wfc_s[(k4 * 4 + 1) * 10 + j]
                      + v.z * wfc_s[(k4 * 4 + 2) * 10 + j] + v.w * wfc_s[(k4 * 4 + 3) * 10 + j];
        }
        #pragma unroll
        for (int j = 0; j < 10; ++j) T1[t][j] = s[j];
    }
    __syncthreads();
    float m[10];
    #pragma unroll
    for (int j = 0; j < 10; ++j) m[j] = 0.0f;
    const float4* row1 = (const float4*)(w_g1 + t * 128);
    #pragma unroll 4
    for (int k4 = 0; k4 < 32; ++k4) {
        float4 v = row1[k4];
        #pragma unroll
        for (int j = 0; j < 10; ++j)
            m[j] += v.x * T1[k4 * 4 + 0][j] + v.y * T1[k4 * 4 + 1][j]
                  + v.z * T1[k4 * 4 + 2][j] + v.w * T1[k4 * 4 + 3][j];
    }
    #pragma unroll
    for (int j = 0; j < 16; ++j)
        M16[j * 256 + t] = (j < 10) ? f2bf(m[j]) : (ushort_t)0;
    if (t < 10) {
        float s1 = 0.0f;
        for (int k2 = 0; k2 < 128; ++k2) s1 += b_g1[k2] * T1[k2][t];
        cc[t] = s1;
        float s2 = 0.0f;
        for (int k3 = 0; k3 < 64; ++k3) s2 += b_g2[k3] * wfc_s[k3 * 10 + t];
        cc[16 + t] = s2 + b_fc[t];
    }
}

// ---------------------------------------------------------------------------
// GRU layer 1 — A-RESIDENT [R9 best-measured config]. One block = 128 rows x
// ALL 256 output cols; X staged ONCE (32 KB rot-swizzled, cvt on the fly),
// jc-loop stages only B (12 KB/phase). 44 KB -> 3 blk/CU.
// [R11 post-mortem: A-in-regs variant spilled at launch_bounds(512,8)
//  (VGPR=32) + uncoalesced frag loads + 4-way ldsw128 conflicts -> 116 us.
//  This LDS-resident form is the best-measured l1.]
// ---------------------------------------------------------------------------
__global__ __launch_bounds__(512, 4) void gru_l1(
    const float* __restrict__ X,         // [N,128] fp32
    const ushort_t* __restrict__ Wf,     // [384,128] bf16
    const ushort_t* __restrict__ Wb,
    const float* __restrict__ bi_f, const float* __restrict__ bh_f,
    const float* __restrict__ bi_b, const float* __restrict__ bh_b,
    ushort_t* __restrict__ Hout)         // [N,256] bf16
{
    __shared__ ushort_t As[2 * 8192];    // X resident: 2 K-regions x [128x64], 32 KB
    __shared__ ushort_t Bs[96 * 64];     // 12 KB per-phase W chunk
    const int tid = threadIdx.x;
    const int m0 = blockIdx.x * 128;
    const int wv = tid >> 6, lane = tid & 63;
    const int lr = lane & 15, lq = lane >> 4;

    // ---- stage X once: 2048 chunks (ci -> region, row, slot), cvt fp32->bf16
    #pragma unroll
    for (int p = 0; p < 4; ++p) {
        int ci = p * 512 + tid;
        int reg = ci >> 10, w = ci & 1023, row = w >> 3, slot = w & 7;
        int g = (slot + row) & 7;
        const float* src = X + (size_t)(m0 + row) * 128 + reg * 64 + g * 8;
        float4 f0 = ((const float4*)src)[0];
        float4 f1 = ((const float4*)src)[1];
        bf16x8 t8;
        t8[0] = (__bf16)f0.x; t8[1] = (__bf16)f0.y; t8[2] = (__bf16)f0.z; t8[3] = (__bf16)f0.w;
        t8[4] = (__bf16)f1.x; t8[5] = (__bf16)f1.y; t8[6] = (__bf16)f1.z; t8[7] = (__bf16)f1.w;
        *(bf16x8*)&As[ci * 8] = t8;
    }
    __syncthreads();

    for (int jc = 0; jc < 8; ++jc) {
        const int dir = jc >> 2;
        const int j0 = (jc & 3) * 32;
        const ushort_t* W = dir ? Wb : Wf;
        const float* b_ih = dir ? bi_b : bi_f;
        const float* b_hh = dir ? bh_b : bh_f;
        const int coloff = dir << 7;

        f32x4 acc[3][2];
        #pragma unroll
        for (int g = 0; g < 3; ++g)
            #pragma unroll
            for (int ct = 0; ct < 2; ++ct)
                #pragma unroll
                for (int e = 0; e < 4; ++e) acc[g][ct][e] = 0.0f;

        for (int t = 0; t < 2; ++t) {
            // stage B: 768 chunks (96 rows x 8 slots), rot-swizzled
            {
                int ci = tid;
                int r96 = ci >> 3, slot = ci & 7, g = (slot + r96) & 7;
                int wr = ((r96 >> 5) << 7) + j0 + (r96 & 31);
                gll16(W + (size_t)wr * 128 + t * 64 + g * 8, &Bs[ci * 8]);
                if (tid < 256) {
                    int ci2 = 512 + tid;
                    int r2 = ci2 >> 3, s2 = ci2 & 7, g2 = (s2 + r2) & 7;
                    int wr2 = ((r2 >> 5) << 7) + j0 + (r2 & 31);
                    gll16(W + (size_t)wr2 * 128 + t * 64 + g2 * 8, &Bs[ci2 * 8]);
                }
            }
            __syncthreads();
            #pragma unroll
            for (int kk = 0; kk < 64; kk += 32) {
                const int g8 = (kk >> 3) + lq;
                bf16x8 a0 = ldsw(&As[t * 8192], wv * 16 + lr, g8);
                #pragma unroll
                for (int g = 0; g < 3; ++g) {
                    #pragma unroll
                    for (int ct = 0; ct < 2; ++ct) {
                        bf16x8 b = ldsw(Bs, g * 32 + ct * 16 + lr, g8);
                        acc[g][ct] = __builtin_amdgcn_mfma_f32_16x16x32_bf16(a0, b, acc[g][ct], 0, 0, 0);
                    }
                }
            }
            __syncthreads();
        }

        // epilogue jc: C/D layout col=lane&15, row=(lane>>4)*4+reg [m89/m91]
        #pragma unroll
        for (int ct = 0; ct < 2; ++ct) {
            const int j = j0 + ct * 16 + lr;
            const float br  = b_ih[j] + b_hh[j];
            const float bz  = b_ih[HDIM + j] + b_hh[HDIM + j];
            const float bn  = b_ih[2 * HDIM + j];
            const float bhn = b_hh[2 * HDIM + j];
            #pragma unroll
            for (int r = 0; r < 4; ++r) {
                const int row = m0 + wv * 16 + lq * 4 + r;
                float rg = fsig(acc[0][ct][r] + br);
                float zg = fsig(acc[1][ct][r] + bz);
                float ng = ftanh(acc[2][ct][r] + bn + rg * bhn);
                ((__bf16*)Hout)[(size_t)row * 256 + coloff + j] = (__bf16)((1.0f - zg) * ng);
            }
        }
    }
}

// ---------------------------------------------------------------------------
// GRU layer 2 + fused z — A-RESIDENT [R9 best-measured config]: h1 tile
// [128,256] staged ONCE into 64 KB LDS (4 rot-swizzled K-regions); jc-loop
// stages only B2. z accumulates IN-REGISTER across all 8 jc (ascending jc =
// same fp32 order as the old zsum) -> writes final Zc (5 MB) directly; no Zp.
// Per-wave h-spill (stride 40, conflict-free) reuses Bs between phases.
// 76 KB LDS -> 2 blk/CU.
// ---------------------------------------------------------------------------
__global__ __launch_bounds__(512, 4) void gru_l2(
    const ushort_t* __restrict__ A,      // h1 [N,256] bf16
    const ushort_t* __restrict__ Wf,     // [384,256] bf16
    const ushort_t* __restrict__ Wb,
    const float* __restrict__ bi_f, const float* __restrict__ bh_f,
    const float* __restrict__ bi_b, const float* __restrict__ bh_b,
    const ushort_t* __restrict__ M16,    // [16,256] bf16
    float* __restrict__ Zc)              // [N,10] fp32 FINAL
{
    __shared__ ushort_t Ah[4 * 8192];    // h1 resident: 4 K-regions, 64 KB
    __shared__ ushort_t Bs[96 * 64];     // 12 KB per-phase W chunk (+ spill reuse)
    const int tid = threadIdx.x;
    const int m0 = blockIdx.x * 128;
    const int wv = tid >> 6, lane = tid & 63;
    const int lr = lane & 15, lq = lane >> 4;

    // ---- stage h1 once: 4096 chunks via gll16
    #pragma unroll
    for (int p = 0; p < 8; ++p) {
        int ci = p * 512 + tid;
        int reg = ci >> 10, w = ci & 1023, row = w >> 3, slot = w & 7;
        int g = (slot + row) & 7;
        gll16(A + (size_t)(m0 + row) * 256 + reg * 64 + g * 8, &Ah[ci * 8]);
    }
    __syncthreads();

    f32x4 z;
    #pragma unroll
    for (int e = 0; e < 4; ++e) z[e] = 0.0f;

    for (int jc = 0; jc < 8; ++jc) {
        const int dir = jc >> 2;
        const int j0 = (jc & 3) * 32;
        const ushort_t* W = dir ? Wb : Wf;
        const float* b_ih = dir ? bi_b : bi_f;
        const float* b_hh = dir ? bh_b : bh_f;
        const int coloff = dir << 7;

        f32x4 acc[3][2];
        #pragma unroll
        for (int g = 0; g < 3; ++g)
            #pragma unroll
            for (int ct = 0; ct < 2; ++ct)
                #pragma unroll
                for (int e = 0; e < 4; ++e) acc[g][ct][e] = 0.0f;

        for (int t = 0; t < 4; ++t) {
            {
                int ci = tid;
                int r96 = ci >> 3, slot = ci & 7, g = (slot + r96) & 7;
                int wr = ((r96 >> 5) << 7) + j0 + (r96 & 31);
                gll16(W + (size_t)wr * 256 + t * 64 + g * 8, &Bs[ci * 8]);
                if (tid < 256) {
                    int ci2 = 512 + tid;
                    int r2 = ci2 >> 3, s2 = ci2 & 7, g2 = (s2 + r2) & 7;
                    int wr2 = ((r2 >> 5) << 7) + j0 + (r2 & 31);
                    gll16(W + (size_t)wr2 * 256 + t * 64 + g2 * 8, &Bs[ci2 * 8]);
                }
            }
            __syncthreads();
            #pragma unroll
            for (int kk = 0; kk < 64; kk += 32) {
                const int g8 = (kk >> 3) + lq;
                bf16x8 a0 = ldsw(&Ah[t * 8192], wv * 16 + lr, g8);
                #pragma unroll
                for (int g = 0; g < 3; ++g) {
                    #pragma unroll
                    for (int ct = 0; ct < 2; ++ct) {
                        bf16x8 b = ldsw(Bs, g * 32 + ct * 16 + lr, g8);
                        acc[g][ct] = __builtin_amdgcn_mfma_f32_16x16x32_bf16(a0, b, acc[g][ct], 0, 0, 0);
                    }
                }
            }
            __syncthreads();
        }

        // z B-frag for this jc: M16[n=lr][k = coloff+j0 + lq*8 .. +7]
        const bf16x8 mb = *(const bf16x8*)&M16[lr * 256 + coloff + j0 + lq * 8];

        // epilogue jc: gates -> per-wave 16x32 spill at stride 40 into Bs
        // (all waves past the compute sync; wave-local write+read, lgkm-ordered)
        ushort_t* hs = &Bs[wv * 640];    // 16 rows * 40 shorts = 1280 B/wave
        #pragma unroll
        for (int ct = 0; ct < 2; ++ct) {
            const int j = j0 + ct * 16 + lr;
            const float br  = b_ih[j] + b_hh[j];
            const float bz  = b_ih[HDIM + j] + b_hh[HDIM + j];
            const float bn  = b_ih[2 * HDIM + j];
            const float bhn = b_hh[2 * HDIM + j];
            #pragma unroll
            for (int r = 0; r < 4; ++r) {
                const int lrow = lq * 4 + r;
                float rg = fsig(acc[0][ct][r] + br);
                float zg = fsig(acc[1][ct][r] + bz);
                float ng = ftanh(acc[2][ct][r] + bn + rg * bhn);
                ((__bf16*)hs)[lrow * 40 + ct * 16 + lr] = (__bf16)((1.0f - zg) * ng);
            }
        }
        // A-frag from own wave band: row = lr, k = lq*8..+7; accumulate z
        bf16x8 ha = *(const bf16x8*)&hs[lr * 40 + lq * 8];
        z = __builtin_amdgcn_mfma_f32_16x16x32_bf16(ha, mb, z, 0, 0, 0);
        __syncthreads();                 // spill reads done before next B stage
    }

    if (lr < 10) {
        #pragma unroll
        for (int r = 0; r < 4; ++r)
            Zc[(size_t)(m0 + wv * 16 + lq * 4 + r) * 10 + lr] = z[r];
    }
}

// ---------------------------------------------------------------------------
// stz: 5-point double-GCN stencil + bias corrections, reading the single
// final Zc slice (l2 pre-sums the 8 partials in-register).
// ---------------------------------------------------------------------------
__device__ __forceinline__ float dcoef(int i) {
    return (i == 0 || i == N_NODES - 1) ? 0.70710678118654752f : 0.57735026918962576f;
}
__global__ __launch_bounds__(256) void stz(
    const float* __restrict__ Zc, float* __restrict__ out,
    const float* __restrict__ cc)
{
    __shared__ __align__(16) float zl[2600];   // 260 nodes x 10
    const int tid = threadIdx.x;
    const int n0 = blockIdx.x * 256;
    const bool edge = (blockIdx.x == 0) || (blockIdx.x == gridDim.x - 1);

    if (!edge) {
        const size_t base4 = ((size_t)n0 * 10 - 20) >> 2;
        const float4* Z4 = (const float4*)Zc;
        for (int i4 = tid; i4 < 650; i4 += 256)
            ((float4*)zl)[i4] = Z4[base4 + i4];
    } else {
        for (int i = tid; i < 2600; i += 256) {
            int nl = i / 10;
            int c = i - nl * 10;
            int n = n0 - 2 + nl;
            zl[i] = (n >= 0 && n < N_NODES) ? Zc[(size_t)n * 10 + c] : 0.0f;
        }
    }
    __syncthreads();

    const int i = n0 + tid;
    const float d_i = dcoef(i);
    float dsum = d_i;
    if (i - 1 >= 0) dsum += dcoef(i - 1);
    if (i + 1 < N_NODES) dsum += dcoef(i + 1);

    #pragma unroll
    for (int c = 0; c < 10; ++c) {
        float accv = 0.0f;
        #pragma unroll
        for (int oj = -1; oj <= 1; ++oj) {
            int j = i + oj;
            if (j < 0 || j >= N_NODES) continue;
            float dj = dcoef(j);
            float wj = 0.0f;
            #pragma unroll
            for (int ok = -1; ok <= 1; ++ok) {
                int k = j + ok;
                wj += dcoef(k) * zl[(tid + 2 + oj + ok) * 10 + c];
            }
            accv += dj * dj * wj;
        }
        out[(size_t)i * 10 + c] = d_i * accv + d_i * dsum * cc[c] + cc[16 + c];
    }
}

extern "C" void kernel_launch(void* const* d_in, const int* in_sizes, int n_in,
                              void* d_out, int out_size, void* d_ws, size_t ws_size,
                              hipStream_t stream) {
    const float* x     = (const float*)d_in[0];
    const float* w_f1  = (const float*)d_in[1];
    const float* bi_f1 = (const float*)d_in[2];
    const float* bh_f1 = (const float*)d_in[3];
    const float* w_b1  = (const float*)d_in[4];
    const float* bi_b1 = (const float*)d_in[5];
    const float* bh_b1 = (const float*)d_in[6];
    const float* w_f2  = (const float*)d_in[7];
    const float* bi_f2 = (const float*)d_in[8];
    const float* bh_f2 = (const float*)d_in[9];
    const float* w_b2  = (const float*)d_in[10];
    const float* bi_b2 = (const float*)d_in[11];
    const float* bh_b2 = (const float*)d_in[12];
    const float* w_g1  = (const float*)d_in[13];
    const float* b_g1  = (const float*)d_in[14];
    const float* w_g2  = (const float*)d_in[15];
    const float* b_g2  = (const float*)d_in[16];
    const float* w_fc  = (const float*)d_in[17];
    const float* b_fc  = (const float*)d_in[18];

    char* ws = (char*)d_ws;
    ushort_t* h1   = (ushort_t*)(ws);                    // [N,256] bf16 (67.1 MB)
    float*    Zc   = (float*)(ws + 67108864);            // [N,10] fp32 (5.24 MB)
    ushort_t* PWF1 = (ushort_t*)(ws + 134217728);        // [384,128] bf16
    ushort_t* PWB1 = PWF1 + 49152;
    ushort_t* PWF2 = PWB1 + 49152;                       // [384,256] bf16
    ushort_t* PWB2 = PWF2 + 98304;
    ushort_t* M16  = PWB2 + 98304;                       // [16,256] bf16
    float*    cc   = (float*)(M16 + 4096);               // cc1[0..9], cc2[16..25]

    prep_all<<<1153, 256, 0, stream>>>(w_f1, w_b1, w_f2, w_b2,
                                       PWF1, PWB1, PWF2, PWB2,
                                       w_g1, b_g1, w_g2, b_g2, w_fc, b_fc,
                                       M16, cc);

    gru_l1<<<N_NODES / 128, 512, 0, stream>>>(
        x, PWF1, PWB1, bi_f1, bh_f1, bi_b1, bh_b1, h1);
    gru_l2<<<N_NODES / 128, 512, 0, stream>>>(
        h1, PWF2, PWB2, bi_f2, bh_f2, bi_b2, bh_b2, M16, Zc);

    stz<<<N_NODES / 256, 256, 0, stream>>>(Zc, (float*)d_out, cc);
}